// Round 1
// 227.258 us; speedup vs baseline: 1.1701x; 1.1701x over previous
//
#include <hip/hip_runtime.h>

// Attention over channel dim: B=16, HW=16384, C=64, fp32.
// scores[b,q,k] = sum_hw Q[b,hw,q]*K[b,hw,k]; attn=softmax_k; out[b,hw,q]=sum_k attn[b,q,k]*V[b,hw,k]
//
// ws layout: partial scores [B][S_SPLIT][64][64] fp32 (8 MB), then attn_t [B][64k][64q] fp32 (256 KB).

#define S_SPLIT 32
#define CHUNK (16384 / S_SPLIT)      // 512 rows per split block
#define TILE_ROWS 32                 // rows staged in LDS per iteration
#define NT (CHUNK / TILE_ROWS)       // 16 tile iterations

// ---------------- Kernel A: partial scores (split-K GEMM, 8x8 register tile, double-buffered) ----------------
// All 4 waves compute the SAME 64x64 (q,k) tile over DISJOINT row subsets
// (r = i*4 + w). T14-style staging: issue next tile's global loads, compute
// current tile, then LDS-write the prefetched data; ONE barrier per iter.
__global__ __launch_bounds__(256) void scores_kernel(
    const float* __restrict__ Q, const float* __restrict__ K,
    float* __restrict__ partial) {
  const int bs = blockIdx.x;            // b * S_SPLIT + s
  const int b = bs / S_SPLIT;
  const int s = bs % S_SPLIT;
  const int tid = threadIdx.x;
  const int w = tid >> 6;               // wave id 0..3
  const int l = tid & 63;               // lane
  const int q0 = (l >> 3) * 8;          // 8 q per lane
  const int k0 = (l & 7) * 8;           // 8 k per lane

  __shared__ union {
    struct { float4 q[2][512]; float4 k[2][512]; } t;  // 32 KB double-buffered tiles
    float red[2][4096];                                // 32 KB cross-wave reduction
  } lds;

  float acc[8][8];
#pragma unroll
  for (int i = 0; i < 8; ++i)
#pragma unroll
    for (int j = 0; j < 8; ++j) acc[i][j] = 0.f;

  const float4* Qg = (const float4*)(Q + ((size_t)b * 16384 + (size_t)s * CHUNK) * 64);
  const float4* Kg = (const float4*)(K + ((size_t)b * 16384 + (size_t)s * CHUNK) * 64);

  // prologue: stage tile 0 into buffer 0
  lds.t.q[0][tid]       = Qg[tid];
  lds.t.q[0][tid + 256] = Qg[tid + 256];
  lds.t.k[0][tid]       = Kg[tid];
  lds.t.k[0][tid + 256] = Kg[tid + 256];

  for (int t = 0; t < NT; ++t) {
    __syncthreads();                    // buf (t&1) ready; buf ((t+1)&1) free
    const int cb = t & 1;

    // issue next tile's global loads (latency hides under this tile's compute)
    float4 pq0, pq1, pk0, pk1;
    if (t + 1 < NT) {
      pq0 = Qg[(t + 1) * 512 + tid];
      pq1 = Qg[(t + 1) * 512 + tid + 256];
      pk0 = Kg[(t + 1) * 512 + tid];
      pk1 = Kg[(t + 1) * 512 + tid + 256];
    }

#pragma unroll
    for (int i = 0; i < 8; ++i) {
      const int r = (i << 2) + w;       // wave w handles rows w,4+w,...,28+w
      float4 qa = lds.t.q[cb][r * 16 + (q0 >> 2)];
      float4 qb = lds.t.q[cb][r * 16 + (q0 >> 2) + 1];
      float4 ka = lds.t.k[cb][r * 16 + (k0 >> 2)];
      float4 kb = lds.t.k[cb][r * 16 + (k0 >> 2) + 1];
      float qv[8] = {qa.x, qa.y, qa.z, qa.w, qb.x, qb.y, qb.z, qb.w};
      float kv[8] = {ka.x, ka.y, ka.z, ka.w, kb.x, kb.y, kb.z, kb.w};
#pragma unroll
      for (int ii = 0; ii < 8; ++ii)
#pragma unroll
        for (int jj = 0; jj < 8; ++jj)
          acc[ii][jj] += qv[ii] * kv[jj];
    }

    // write the prefetched tile into the other buffer (completes before next barrier)
    if (t + 1 < NT) {
      const int nb = (t + 1) & 1;
      lds.t.q[nb][tid]       = pq0;
      lds.t.q[nb][tid + 256] = pq1;
      lds.t.k[nb][tid]       = pk0;
      lds.t.k[nb][tid + 256] = pk1;
    }
  }

  // ---- cross-wave reduction: waves 2,3 publish; waves 0,1 add; halves summed on store ----
  __syncthreads();                      // all waves done reading tile LDS
  if (w >= 2) {
    float4* dst = (float4*)lds.red[w - 2];
#pragma unroll
    for (int i = 0; i < 8; ++i) {
      dst[(q0 + i) * 16 + (k0 >> 2)]     = make_float4(acc[i][0], acc[i][1], acc[i][2], acc[i][3]);
      dst[(q0 + i) * 16 + (k0 >> 2) + 1] = make_float4(acc[i][4], acc[i][5], acc[i][6], acc[i][7]);
    }
  }
  __syncthreads();
  if (w < 2) {
    float4* dst = (float4*)lds.red[w];
#pragma unroll
    for (int i = 0; i < 8; ++i) {
      float4 u = dst[(q0 + i) * 16 + (k0 >> 2)];
      float4 v = dst[(q0 + i) * 16 + (k0 >> 2) + 1];
      dst[(q0 + i) * 16 + (k0 >> 2)]     = make_float4(u.x + acc[i][0], u.y + acc[i][1], u.z + acc[i][2], u.w + acc[i][3]);
      dst[(q0 + i) * 16 + (k0 >> 2) + 1] = make_float4(v.x + acc[i][4], v.y + acc[i][5], v.z + acc[i][6], v.w + acc[i][7]);
    }
  }
  __syncthreads();
  // cooperative coalesced store of the reduced 64x64 tile
  float4* p4 = (float4*)(partial + (size_t)bs * 4096);
  const float4* r0 = (const float4*)lds.red[0];
  const float4* r1 = (const float4*)lds.red[1];
#pragma unroll
  for (int c = 0; c < 4; ++c) {
    float4 x = r0[c * 256 + tid];
    float4 y = r1[c * 256 + tid];
    p4[c * 256 + tid] = make_float4(x.x + y.x, x.y + y.y, x.z + y.z, x.w + y.w);
  }
}

// ---------------- Kernel B: reduce partials + softmax over k, store TRANSPOSED attn_t[b][k][q] ----------------
// Block = (b, q-quad): 1 wave. lane = (ql 0..3, k4 0..15); float4-coalesced
// partial reads (1 KB/wave/s), 16-lane shuffle reduce per q row.
__global__ __launch_bounds__(64) void softmax_kernel(
    const float* __restrict__ partial, float* __restrict__ attn_t) {
  const int blk = blockIdx.x;           // b*16 + qquad
  const int b = blk >> 4;
  const int q0 = (blk & 15) * 4;
  const int lane = threadIdx.x;
  const int ql = lane >> 4;             // 0..3  (q = q0+ql)
  const int k4 = lane & 15;             // float4 column

  const float4* P = (const float4*)partial;
  float4 v = make_float4(0.f, 0.f, 0.f, 0.f);
  for (int s = 0; s < S_SPLIT; ++s) {
    float4 t = P[((size_t)(b * S_SPLIT + s) * 64 + q0 + ql) * 16 + k4];
    v.x += t.x; v.y += t.y; v.z += t.z; v.w += t.w;
  }

  float m = fmaxf(fmaxf(v.x, v.y), fmaxf(v.z, v.w));
#pragma unroll
  for (int off = 8; off > 0; off >>= 1)
    m = fmaxf(m, __shfl_xor(m, off, 64));   // reduce across the 16 lanes sharing q
  float4 e = make_float4(__expf(v.x - m), __expf(v.y - m), __expf(v.z - m), __expf(v.w - m));
  float sum = e.x + e.y + e.z + e.w;
#pragma unroll
  for (int off = 8; off > 0; off >>= 1)
    sum += __shfl_xor(sum, off, 64);
  const float inv = 1.f / sum;

  float* A = attn_t + (size_t)b * 4096;     // [k][q] layout
  A[(4 * k4 + 0) * 64 + q0 + ql] = e.x * inv;
  A[(4 * k4 + 1) * 64 + q0 + ql] = e.y * inv;
  A[(4 * k4 + 2) * 64 + q0 + ql] = e.z * inv;
  A[(4 * k4 + 3) * 64 + q0 + ql] = e.w * inv;
}

// ---------------- Kernel C: out = V * attn_t (register-tiled GEMM, 8x4 per thread) ----------------
// Block = 128 rows x 64 q. thread (g = tid>>4, qg = tid&15) computes rows
// {16*i+g, i=0..7} x cols {4*qg..4*qg+3}. V in LDS padded to 68 floats/row
// (banks 4g+4k4: conflict-free); attn_t rows read as float4 over q (banks
// 4qg: 2-way, free). 192 ds_read_b128 : 2048 FMA per thread, 32 independent
// accumulators, coalesced float4 stores (4 x 256 B segments per wave).
__global__ __launch_bounds__(256) void out_kernel(
    const float* __restrict__ V, const float* __restrict__ attn_t,
    float* __restrict__ out) {
  const int blk = blockIdx.x;
  const int b = blk >> 7;               // 128 tiles of 128 rows per batch
  const int tile = blk & 127;
  const int tid = threadIdx.x;
  const int g = tid >> 4;               // row group 0..15
  const int qg = tid & 15;              // q group 0..15

  __shared__ float4 Vl[128 * 17];       // row r at float4 index r*17 (68-float pad)  34 KB
  __shared__ float4 Al[64 * 16];        // attn_t[k][q] row-major, no pad             16 KB

  const float4* Vg = (const float4*)(V + ((size_t)b * 16384 + (size_t)tile * 128) * 64);
#pragma unroll
  for (int u = 0; u < 8; ++u) {
    const int idx = u * 256 + tid;      // 0..2047 float4 of the 128x64 tile
    Vl[(idx >> 4) * 17 + (idx & 15)] = Vg[idx];
  }
  const float4* Ag = (const float4*)(attn_t + (size_t)b * 4096);
#pragma unroll
  for (int u = 0; u < 4; ++u)
    Al[u * 256 + tid] = Ag[u * 256 + tid];
  __syncthreads();

  float acc[8][4];
#pragma unroll
  for (int i = 0; i < 8; ++i)
#pragma unroll
    for (int j = 0; j < 4; ++j) acc[i][j] = 0.f;

  for (int k4 = 0; k4 < 16; ++k4) {
    const float4 a0 = Al[(4 * k4 + 0) * 16 + qg];   // attn[q0..q0+3][4k4+0]
    const float4 a1 = Al[(4 * k4 + 1) * 16 + qg];
    const float4 a2 = Al[(4 * k4 + 2) * 16 + qg];
    const float4 a3 = Al[(4 * k4 + 3) * 16 + qg];
#pragma unroll
    for (int i = 0; i < 8; ++i) {
      const float4 v = Vl[(i * 16 + g) * 17 + k4];  // V[row][4k4..4k4+3]
      acc[i][0] += v.x * a0.x + v.y * a1.x + v.z * a2.x + v.w * a3.x;
      acc[i][1] += v.x * a0.y + v.y * a1.y + v.z * a2.y + v.w * a3.y;
      acc[i][2] += v.x * a0.z + v.y * a1.z + v.z * a2.z + v.w * a3.z;
      acc[i][3] += v.x * a0.w + v.y * a1.w + v.z * a2.w + v.w * a3.w;
    }
  }

  float4* og = (float4*)(out + ((size_t)b * 16384 + (size_t)tile * 128) * 64);
#pragma unroll
  for (int i = 0; i < 8; ++i) {
    const int row = i * 16 + g;
    og[row * 16 + qg] = make_float4(acc[i][0], acc[i][1], acc[i][2], acc[i][3]);
  }
}

extern "C" void kernel_launch(void* const* d_in, const int* in_sizes, int n_in,
                              void* d_out, int out_size, void* d_ws, size_t ws_size,
                              hipStream_t stream) {
  const float* Q = (const float*)d_in[0];
  const float* K = (const float*)d_in[1];
  const float* V = (const float*)d_in[2];
  float* out = (float*)d_out;

  float* partial = (float*)d_ws;                           // 16*S_SPLIT*4096 floats = 8 MB
  float* attn_t = partial + (size_t)16 * S_SPLIT * 4096;   // 256 KB, [b][k][q]

  scores_kernel<<<16 * S_SPLIT, 256, 0, stream>>>(Q, K, partial);
  softmax_kernel<<<16 * 16, 64, 0, stream>>>(partial, attn_t);
  out_kernel<<<16 * 128, 256, 0, stream>>>(V, attn_t, out);
}